// Round 12
// baseline (701.363 us; speedup 1.0000x reference)
//
#include <hip/hip_runtime.h>
#include <hip/hip_cooperative_groups.h>

#define N_NODES 100000
#define N_EDGES 1600000
#define IN_DIM 32
#define HID_DIM 64
#define OUT_DIM 8
#define BK 64                         // dst nodes per bucket
#define NBKT ((N_NODES + BK - 1) / BK)    // 1563
#define QC 1280                       // per-bucket total cap (mean 1024, +8 sigma)
#define QCP 224                       // per-(bucket,XCD-partition) cap
#define QSTR 2048                     // qcnt partition stride
#define CHUNK 4096                    // edges per partition block
#define NCHUNK ((N_EDGES + CHUNK - 1) / CHUNK)   // 391

typedef unsigned short u16;
typedef unsigned int u32;
typedef unsigned long long ull;

__device__ __forceinline__ float bf2f(u16 v) {
    return __uint_as_float(((u32)v) << 16);
}

__device__ __forceinline__ u16 f2bf(float f) {
    u32 u = __float_as_uint(f);
    u32 lsb = (u >> 16) & 1u;
    u += 0x7fffu + lsb;
    return (u16)(u >> 16);
}

__device__ __forceinline__ float ldf(const void* p, size_t i, int bf) {
    return bf ? bf2f(((const u16*)p)[i]) : ((const float*)p)[i];
}

// ============================================================================
// FUSED cooperative kernel (R12): phases separated by grid.sync().
//   P0: qcnt zero + weight transpose.
//   P1: blocks 0..390: R11-verbatim edge partition (XCD-partitioned queues).
//   P2/3: R11-verbatim k_l1 (stage+sort+gather+dense+proj).
//   P4: layer-2 gather REUSING LDS srt/pos/hist (k_l2 sort deleted).
// LDS union 22.4KB -> 7 blocks/CU x 256 CU = 1792 >= 1563 co-resident.
// ============================================================================
union ShU {
    struct { int hist[NBKT], gbase[NBKT], lcur[NBKT]; } p;   // 18.8 KB
    struct {
        int hist[BK], pos[BK], pcur[BK];
        int mp[8], mbase[8], mtv;
        u32 raw[QC], srt[QC];
        float xs[BK][IN_DIM];
        float aggw[4][2][IN_DIM];
        float hb[8][HID_DIM + 1];
    } l;                                                      // 22.4 KB
};

__global__ __launch_bounds__(256, 7) void k_fused(
    const int* __restrict__ ei, const u32* __restrict__ xw,
    const void* __restrict__ W1l, const void* __restrict__ b1,
    const void* __restrict__ W1r,
    const void* __restrict__ W2l, const void* __restrict__ b2,
    const void* __restrict__ W2r,
    int* __restrict__ qcnt, u32* __restrict__ qbuf,
    float* __restrict__ tW1l, float* __restrict__ tW1r,
    float* __restrict__ tW2l, float* __restrict__ tW2r,
    float* __restrict__ tb1, float* __restrict__ tb2,
    u16* __restrict__ gbuf, float* __restrict__ rbuf,
    void* __restrict__ out)
{
    __shared__ ShU u;
    __shared__ int shv_, bfv_;
    cooperative_groups::grid_group grid = cooperative_groups::this_grid();

    int t = threadIdx.x;
    int b = blockIdx.x;

    if (t < 64) {   // dtype probes (proven), once for the whole kernel
        int v = ei[2 * t + 1];
        ull m1 = __ballot(v == 0);
        u32 wd = xw[t];
        u32 bb = (wd >> 8) & 0x7fu;
        ull m2 = __ballot(bb >= 0x38u && bb <= 0x41u);
        if (t == 0) {
            shv_ = (m1 == ~0ULL) ? 1 : 0;
            bfv_ = (__popcll(m2) >= 56) ? 1 : 0;
        }
    }
    __syncthreads();
    int sh = shv_, bf = bfv_;

    // ---- Phase 0: qcnt zero + weight transpose ----
    {
        int i = b * 256 + t;
        if (i < 8 * QSTR) qcnt[i] = 0;
    }
    if (b < 16) {                 // weight transpose duty (R11-proven)
        for (int i = b * 256 + t; i < HID_DIM * IN_DIM; i += 16 * 256) {
            int o = i / IN_DIM, k = i % IN_DIM;
            tW1l[k * HID_DIM + o] = ldf(W1l, i, bf);
            tW1r[k * HID_DIM + o] = ldf(W1r, i, bf);
        }
        for (int i = b * 256 + t; i < OUT_DIM * HID_DIM; i += 16 * 256) {
            int o = i / HID_DIM, k = i % HID_DIM;
            tW2l[k * OUT_DIM + o] = ldf(W2l, i, bf);
            tW2r[k * OUT_DIM + o] = ldf(W2r, i, bf);
        }
        if (b == 0) {
            if (t < HID_DIM) tb1[t] = ldf(b1, t, bf);
            if (t < OUT_DIM) tb2[t] = ldf(b2, t, bf);
        }
    }
    grid.sync();

    // ---- Phase 1: edge partition (blocks 0..390; R11-verbatim body) ----
    if (b < NCHUNK) {
        int part = b & 7;         // XCD proxy (round-robin dispatch)
        for (int i = t; i < NBKT; i += 256) { u.p.hist[i] = 0; u.p.lcur[i] = 0; }
        __syncthreads();
        int e0 = b * CHUNK;
        int myd[16], mys[16];
        #pragma unroll
        for (int i = 0; i < 16; i++) {
            int e = e0 + i * 256 + t;
            if (e < N_EDGES) {
                size_t off = (size_t)e << sh;
                mys[i] = ei[off];
                int d = ei[((size_t)N_EDGES << sh) + off];
                myd[i] = d;
                atomicAdd(&u.p.hist[d >> 6], 1);
            } else myd[i] = -1;
        }
        __syncthreads();
        for (int i = t; i < NBKT; i += 256) {
            int h = u.p.hist[i];
            u.p.gbase[i] = h ? atomicAdd(&qcnt[part * QSTR + i], h) : 0;
        }
        __syncthreads();
        #pragma unroll
        for (int i = 0; i < 16; i++) {
            int d = myd[i];
            if (d >= 0) {
                int bk = d >> 6;
                int p = u.p.gbase[bk] + atomicAdd(&u.p.lcur[bk], 1);
                if (p < QCP)
                    qbuf[((size_t)part * NBKT + bk) * QCP + p] =
                        ((u32)mys[i] << 6) | (u32)(d & 63);
            }
        }
    }
    grid.sync();

    // ---- Phase 2/3: layer 1 (R11-verbatim k_l1 body) ----
    int nb = b * BK;
    if (t < BK) u.l.hist[t] = 0;
    if (t < 8) {
        int v = qcnt[t * QSTR + b];
        if (v < 0) v = 0;
        if (v > QCP) v = QCP;
        u.l.mp[t] = v;
    }
    __syncthreads();
    if (t == 0) {       // sequential clamp so total fits raw/srt (QC)
        int s = 0;
        for (int p = 0; p < 8; p++) {
            u.l.mbase[p] = s;
            int v = u.l.mp[p];
            if (s + v > QC) v = QC - s;
            if (v < 0) v = 0;
            u.l.mp[p] = v; s += v;
        }
        u.l.mtv = s;
    }
    __syncthreads();
    int m = u.l.mtv;

    // stage the 8 partition segments into raw[] (plain loads: cross-XCD data)
    for (int p = 0; p < 8; p++) {
        const u32* qp = qbuf + ((size_t)p * NBKT + b) * QCP;
        int mpp = u.l.mp[p], mb = u.l.mbase[p];
        for (int i = t; i < mpp; i += 256)
            u.l.raw[mb + i] = qp[i];
    }

    // stage self rows -> xs (f32), guarded for the partial last bucket
    const void* x = (const void*)xw;
    if (bf) {
        const u32* xr = xw + (size_t)nb * (IN_DIM / 2);
        int lim = ((N_NODES - nb < BK) ? (N_NODES - nb) : BK) * (IN_DIM / 2);
        for (int i = t; i < BK * (IN_DIM / 2); i += 256) {
            u32 w = (i < lim) ? xr[i] : 0u;
            int r = i >> 4, c = i & 15;
            u.l.xs[r][2 * c]     = bf2f((u16)w);
            u.l.xs[r][2 * c + 1] = bf2f((u16)(w >> 16));
        }
    } else {
        const float* xr = (const float*)x + (size_t)nb * IN_DIM;
        int lim = ((N_NODES - nb < BK) ? (N_NODES - nb) : BK) * IN_DIM;
        for (int i = t; i < BK * IN_DIM; i += 256)
            u.l.xs[i >> 5][i & 31] = (i < lim) ? xr[i] : 0.0f;
    }
    __syncthreads();

    // counting sort (R8-proven): histogram -> 1-wave scan -> scatter
    for (int i = t; i < m; i += 256)
        atomicAdd(&u.l.hist[u.l.raw[i] & 63], 1);
    __syncthreads();
    if (t < 64) {
        int v = u.l.hist[t];
        int inc = v;
        #pragma unroll
        for (int o = 1; o < 64; o <<= 1) {
            int y = __shfl_up(inc, o, 64);
            if (t >= o) inc += y;
        }
        int ex = inc - v;
        u.l.pos[t] = ex; u.l.pcur[t] = ex;
    }
    __syncthreads();
    for (int i = t; i < m; i += 256) {
        u32 uu = u.l.raw[i];
        int p = atomicAdd(&u.l.pcur[uu & 63], 1);
        u.l.srt[p] = uu >> 6;
    }
    __syncthreads();

    // per-pair gather (R8-proven ILP-4 loop) + dense + proj
    int wid = t >> 6, lane = t & 63;               // wid 0..3
    int half = lane >> 5, g2 = (lane >> 3) & 3, l = lane & 7;
    int o = lane;
    float bb2 = tb1[o];
    for (int pr = 0; pr < 8; pr++) {
        int s0 = pr * 8 + wid * 2;
        int ns = s0 + half;
        int st = u.l.pos[ns], deg = u.l.hist[ns];
        float a0 = 0, a1 = 0, a2 = 0, a3 = 0;
        float c0 = 0, c1 = 0, c2 = 0, c3 = 0;
        float d0 = 0, d1 = 0, d2 = 0, d3 = 0;
        float e0 = 0, e1 = 0, e2 = 0, e3 = 0;
        int j = g2;
        for (; j + 12 < deg; j += 16) {   // 4 independent neighbor loads
            int sA = (int)u.l.srt[st + j];
            int sB = (int)u.l.srt[st + j + 4];
            int sC = (int)u.l.srt[st + j + 8];
            int sD = (int)u.l.srt[st + j + 12];
            if (bf) {
                ushort4 vA = reinterpret_cast<const ushort4*>((const u16*)x + (size_t)sA * IN_DIM)[l];
                ushort4 vB = reinterpret_cast<const ushort4*>((const u16*)x + (size_t)sB * IN_DIM)[l];
                ushort4 vC = reinterpret_cast<const ushort4*>((const u16*)x + (size_t)sC * IN_DIM)[l];
                ushort4 vD = reinterpret_cast<const ushort4*>((const u16*)x + (size_t)sD * IN_DIM)[l];
                a0 += bf2f(vA.x); a1 += bf2f(vA.y); a2 += bf2f(vA.z); a3 += bf2f(vA.w);
                c0 += bf2f(vB.x); c1 += bf2f(vB.y); c2 += bf2f(vB.z); c3 += bf2f(vB.w);
                d0 += bf2f(vC.x); d1 += bf2f(vC.y); d2 += bf2f(vC.z); d3 += bf2f(vC.w);
                e0 += bf2f(vD.x); e1 += bf2f(vD.y); e2 += bf2f(vD.z); e3 += bf2f(vD.w);
            } else {
                float4 vA = reinterpret_cast<const float4*>((const float*)x + (size_t)sA * IN_DIM)[l];
                float4 vB = reinterpret_cast<const float4*>((const float*)x + (size_t)sB * IN_DIM)[l];
                float4 vC = reinterpret_cast<const float4*>((const float*)x + (size_t)sC * IN_DIM)[l];
                float4 vD = reinterpret_cast<const float4*>((const float*)x + (size_t)sD * IN_DIM)[l];
                a0 += vA.x; a1 += vA.y; a2 += vA.z; a3 += vA.w;
                c0 += vB.x; c1 += vB.y; c2 += vB.z; c3 += vB.w;
                d0 += vC.x; d1 += vC.y; d2 += vC.z; d3 += vC.w;
                e0 += vD.x; e1 += vD.y; e2 += vD.z; e3 += vD.w;
            }
        }
        for (; j + 4 < deg; j += 8) {     // 2-way remainder
            int sA = (int)u.l.srt[st + j];
            int sB = (int)u.l.srt[st + j + 4];
            if (bf) {
                ushort4 vA = reinterpret_cast<const ushort4*>((const u16*)x + (size_t)sA * IN_DIM)[l];
                ushort4 vB = reinterpret_cast<const ushort4*>((const u16*)x + (size_t)sB * IN_DIM)[l];
                a0 += bf2f(vA.x); a1 += bf2f(vA.y); a2 += bf2f(vA.z); a3 += bf2f(vA.w);
                c0 += bf2f(vB.x); c1 += bf2f(vB.y); c2 += bf2f(vB.z); c3 += bf2f(vB.w);
            } else {
                float4 vA = reinterpret_cast<const float4*>((const float*)x + (size_t)sA * IN_DIM)[l];
                float4 vB = reinterpret_cast<const float4*>((const float*)x + (size_t)sB * IN_DIM)[l];
                a0 += vA.x; a1 += vA.y; a2 += vA.z; a3 += vA.w;
                c0 += vB.x; c1 += vB.y; c2 += vB.z; c3 += vB.w;
            }
        }
        if (j < deg) {                    // tail (at most one per group)
            int s = (int)u.l.srt[st + j];
            if (bf) {
                ushort4 vv = reinterpret_cast<const ushort4*>((const u16*)x + (size_t)s * IN_DIM)[l];
                a0 += bf2f(vv.x); a1 += bf2f(vv.y); a2 += bf2f(vv.z); a3 += bf2f(vv.w);
            } else {
                float4 vv = reinterpret_cast<const float4*>((const float*)x + (size_t)s * IN_DIM)[l];
                a0 += vv.x; a1 += vv.y; a2 += vv.z; a3 += vv.w;
            }
        }
        a0 += c0 + d0 + e0;
        a1 += c1 + d1 + e1;
        a2 += c2 + d2 + e2;
        a3 += c3 + d3 + e3;
        a0 += __shfl_xor(a0, 8, 64);  a0 += __shfl_xor(a0, 16, 64);
        a1 += __shfl_xor(a1, 8, 64);  a1 += __shfl_xor(a1, 16, 64);
        a2 += __shfl_xor(a2, 8, 64);  a2 += __shfl_xor(a2, 16, 64);
        a3 += __shfl_xor(a3, 8, 64);  a3 += __shfl_xor(a3, 16, 64);
        if (g2 == 0) {                    // wave-private: no barrier needed
            u.l.aggw[wid][half][4 * l + 0] = a0; u.l.aggw[wid][half][4 * l + 1] = a1;
            u.l.aggw[wid][half][4 * l + 2] = a2; u.l.aggw[wid][half][4 * l + 3] = a3;
        }
        // dense layer 1 (each lane = output o, both nodes of the pair)
        float rd0 = 1.0f / fmaxf((float)u.l.hist[s0], 1.0f);
        float rd1 = 1.0f / fmaxf((float)u.l.hist[s0 + 1], 1.0f);
        float acc0 = bb2, acc1 = bb2;
        #pragma unroll 8
        for (int k = 0; k < IN_DIM; k++) {
            float wl = tW1l[k * HID_DIM + o];
            float wr = tW1r[k * HID_DIM + o];
            acc0 += (u.l.aggw[wid][0][k] * rd0) * wl + u.l.xs[s0][k] * wr;
            acc1 += (u.l.aggw[wid][1][k] * rd1) * wl + u.l.xs[s0 + 1][k] * wr;
        }
        u.l.hb[wid * 2][o]     = fmaxf(acc0, 0.0f);   // wave-private rows
        u.l.hb[wid * 2 + 1][o] = fmaxf(acc1, 0.0f);
        // layer-2 projections: g = h@W2l^T (bf16-packed), r = h@W2r^T + b2
        int hs = wid * 2 + half;
        float ga = 0.0f, ra = 0.0f;
        #pragma unroll 4
        for (int mm = 0; mm < 16; mm++) {
            int k = g2 * 16 + mm;
            float hv = u.l.hb[hs][k];
            ga += hv * tW2l[k * OUT_DIM + l];
            ra += hv * tW2r[k * OUT_DIM + l];
        }
        ga += __shfl_xor(ga, 8, 64);  ga += __shfl_xor(ga, 16, 64);
        ra += __shfl_xor(ra, 8, 64);  ra += __shfl_xor(ra, 16, 64);
        int n = nb + ns;
        if (g2 == 0 && n < N_NODES) {
            gbuf[(size_t)n * OUT_DIM + l] = f2bf(ga);      // plain stores:
            rbuf[(size_t)n * OUT_DIM + l] = ra + tb2[l];   // read after grid.sync
        }
    }
    grid.sync();

    // ---- Phase 4: layer 2 — REUSE LDS srt/pos/hist (no re-sort) ----
    {
        int grp = t >> 3, ll = t & 7;         // 32 groups x 8 lanes
        for (int r = 0; r < 2; r++) {
            int ns = grp * 2 + r;             // node slot 0..63
            int st = u.l.pos[ns], deg = u.l.hist[ns];
            float a0 = 0.0f, a1 = 0.0f, a2 = 0.0f, a3 = 0.0f;
            int j = 0;
            for (; j + 3 < deg; j += 4) {
                int v0 = (int)u.l.srt[st + j];
                int v1 = (int)u.l.srt[st + j + 1];
                int v2 = (int)u.l.srt[st + j + 2];
                int v3 = (int)u.l.srt[st + j + 3];
                a0 += bf2f(gbuf[(size_t)v0 * OUT_DIM + ll]);
                a1 += bf2f(gbuf[(size_t)v1 * OUT_DIM + ll]);
                a2 += bf2f(gbuf[(size_t)v2 * OUT_DIM + ll]);
                a3 += bf2f(gbuf[(size_t)v3 * OUT_DIM + ll]);
            }
            for (; j < deg; j++) a0 += bf2f(gbuf[(size_t)u.l.srt[st + j] * OUT_DIM + ll]);
            int n = nb + ns;
            if (n < N_NODES) {
                float res = (a0 + a1 + a2 + a3) / fmaxf((float)deg, 1.0f)
                          + rbuf[(size_t)n * OUT_DIM + ll];
                size_t oi = (size_t)n * OUT_DIM + ll;
                if (bf) ((u16*)out)[oi] = f2bf(res);
                else    ((float*)out)[oi] = res;
            }
        }
    }
}

// ============================================================================
// FALLBACK path: R11-proven 3-kernel pipeline (213.5us), used if the
// cooperative launch is rejected (e.g. by graph capture).
// ============================================================================
__global__ __launch_bounds__(256) void k_part2(
    const int* __restrict__ ei, const u32* __restrict__ xw,
    const void* __restrict__ W1l, const void* __restrict__ b1,
    const void* __restrict__ W1r,
    const void* __restrict__ W2l, const void* __restrict__ b2,
    const void* __restrict__ W2r,
    int* __restrict__ qcnt, u32* __restrict__ qbuf,
    float* __restrict__ tW1l, float* __restrict__ tW1r,
    float* __restrict__ tW2l, float* __restrict__ tW2r,
    float* __restrict__ tb1, float* __restrict__ tb2)
{
    __shared__ int shv, bfv;
    __shared__ int hist[NBKT], gbase[NBKT], lcur[NBKT];
    int t = threadIdx.x;
    int part = blockIdx.x & 7;
    if (t < 64) {
        int v = ei[2 * t + 1];
        ull m1 = __ballot(v == 0);
        u32 wd = xw[t];
        u32 b = (wd >> 8) & 0x7fu;
        ull m2 = __ballot(b >= 0x38u && b <= 0x41u);
        if (t == 0) {
            shv = (m1 == ~0ULL) ? 1 : 0;
            bfv = (__popcll(m2) >= 56) ? 1 : 0;
        }
    }
    for (int i = t; i < NBKT; i += 256) { hist[i] = 0; lcur[i] = 0; }
    __syncthreads();
    int sh = shv, bf = bfv;

    if (blockIdx.x < 16) {
        for (int i = blockIdx.x * 256 + t; i < HID_DIM * IN_DIM; i += 16 * 256) {
            int o = i / IN_DIM, k = i % IN_DIM;
            tW1l[k * HID_DIM + o] = ldf(W1l, i, bf);
            tW1r[k * HID_DIM + o] = ldf(W1r, i, bf);
        }
        for (int i = blockIdx.x * 256 + t; i < OUT_DIM * HID_DIM; i += 16 * 256) {
            int o = i / HID_DIM, k = i % HID_DIM;
            tW2l[k * OUT_DIM + o] = ldf(W2l, i, bf);
            tW2r[k * OUT_DIM + o] = ldf(W2r, i, bf);
        }
        if (blockIdx.x == 0) {
            if (t < HID_DIM) tb1[t] = ldf(b1, t, bf);
            if (t < OUT_DIM) tb2[t] = ldf(b2, t, bf);
        }
    }

    int e0 = blockIdx.x * CHUNK;
    int myd[16], mys[16];
    #pragma unroll
    for (int i = 0; i < 16; i++) {
        int e = e0 + i * 256 + t;
        if (e < N_EDGES) {
            size_t off = (size_t)e << sh;
            mys[i] = __builtin_nontemporal_load(&ei[off]);
            int d = __builtin_nontemporal_load(&ei[((size_t)N_EDGES << sh) + off]);
            myd[i] = d;
            atomicAdd(&hist[d >> 6], 1);
        } else myd[i] = -1;
    }
    __syncthreads();
    for (int i = t; i < NBKT; i += 256) {
        int h = hist[i];
        gbase[i] = h ? atomicAdd(&qcnt[part * QSTR + i], h) : 0;
    }
    __syncthreads();
    #pragma unroll
    for (int i = 0; i < 16; i++) {
        int d = myd[i];
        if (d >= 0) {
            int bk = d >> 6;
            int p = gbase[bk] + atomicAdd(&lcur[bk], 1);
            if (p < QCP)
                qbuf[((size_t)part * NBKT + bk) * QCP + p] =
                    ((u32)mys[i] << 6) | (u32)(d & 63);
        }
    }
}

__global__ __launch_bounds__(256, 4) void k_l1(
    const void* __restrict__ x,
    const int* __restrict__ qcnt, const u32* __restrict__ qbuf,
    const float* __restrict__ tW1l, const float* __restrict__ tW1r,
    const float* __restrict__ tW2l, const float* __restrict__ tW2r,
    const float* __restrict__ tb1, const float* __restrict__ tb2,
    u16* __restrict__ gbuf, float* __restrict__ rbuf,
    const u32* __restrict__ xw)
{
    __shared__ int hist[BK], pos[BK], pcur[BK];
    __shared__ int mp[8], mbase[8], mtv;
    __shared__ u32 raw[QC];
    __shared__ u32 srt[QC];
    __shared__ float xs[BK][IN_DIM];
    __shared__ float aggw[4][2][IN_DIM];
    __shared__ float hb[8][HID_DIM + 1];
    __shared__ int bfv;

    int t = threadIdx.x;
    if (t < 64) {
        u32 wd = xw[t];
        u32 b = (wd >> 8) & 0x7fu;
        ull m2 = __ballot(b >= 0x38u && b <= 0x41u);
        if (t == 0) bfv = (__popcll(m2) >= 56) ? 1 : 0;
    }
    if (t < BK) hist[t] = 0;
    int b = blockIdx.x, nb = b * BK;
    if (t < 8) {
        int v = qcnt[t * QSTR + b];
        if (v < 0) v = 0;
        if (v > QCP) v = QCP;
        mp[t] = v;
    }
    __syncthreads();
    int bf = bfv;
    if (t == 0) {
        int s = 0;
        for (int p = 0; p < 8; p++) {
            mbase[p] = s;
            int v = mp[p];
            if (s + v > QC) v = QC - s;
            if (v < 0) v = 0;
            mp[p] = v; s += v;
        }
        mtv = s;
    }
    __syncthreads();
    int m = mtv;

    for (int p = 0; p < 8; p++) {
        const u32* qp = qbuf + ((size_t)p * NBKT + b) * QCP;
        int mpp = mp[p], mb = mbase[p];
        for (int i = t; i < mpp; i += 256)
            raw[mb + i] = __builtin_nontemporal_load(&qp[i]);
    }

    if (bf) {
        const u32* xr = (const u32*)x + (size_t)nb * (IN_DIM / 2);
        int lim = ((N_NODES - nb < BK) ? (N_NODES - nb) : BK) * (IN_DIM / 2);
        for (int i = t; i < BK * (IN_DIM / 2); i += 256) {
            u32 w = (i < lim) ? xr[i] : 0u;
            int r = i >> 4, c = i & 15;
            xs[r][2 * c]     = bf2f((u16)w);
            xs[r][2 * c + 1] = bf2f((u16)(w >> 16));
        }
    } else {
        const float* xr = (const float*)x + (size_t)nb * IN_DIM;
        int lim = ((N_NODES - nb < BK) ? (N_NODES - nb) : BK) * IN_DIM;
        for (int i = t; i < BK * IN_DIM; i += 256)
            xs[i >> 5][i & 31] = (i < lim) ? xr[i] : 0.0f;
    }
    __syncthreads();

    for (int i = t; i < m; i += 256)
        atomicAdd(&hist[raw[i] & 63], 1);
    __syncthreads();
    if (t < 64) {
        int v = hist[t];
        int inc = v;
        #pragma unroll
        for (int o = 1; o < 64; o <<= 1) {
            int y = __shfl_up(inc, o, 64);
            if (t >= o) inc += y;
        }
        int ex = inc - v;
        pos[t] = ex; pcur[t] = ex;
    }
    __syncthreads();
    for (int i = t; i < m; i += 256) {
        u32 u = raw[i];
        int p = atomicAdd(&pcur[u & 63], 1);
        srt[p] = u >> 6;
    }
    __syncthreads();

    int wid = t >> 6, lane = t & 63;
    int half = lane >> 5, g2 = (lane >> 3) & 3, l = lane & 7;
    int o = lane;
    float bb = tb1[o];
    for (int pr = 0; pr < 8; pr++) {
        int s0 = pr * 8 + wid * 2;
        int ns = s0 + half;
        int st = pos[ns], deg = hist[ns];
        float a0 = 0, a1 = 0, a2 = 0, a3 = 0;
        float c0 = 0, c1 = 0, c2 = 0, c3 = 0;
        float d0 = 0, d1 = 0, d2 = 0, d3 = 0;
        float e0 = 0, e1 = 0, e2 = 0, e3 = 0;
        int j = g2;
        for (; j + 12 < deg; j += 16) {
            int sA = (int)srt[st + j];
            int sB = (int)srt[st + j + 4];
            int sC = (int)srt[st + j + 8];
            int sD = (int)srt[st + j + 12];
            if (bf) {
                ushort4 vA = reinterpret_cast<const ushort4*>((const u16*)x + (size_t)sA * IN_DIM)[l];
                ushort4 vB = reinterpret_cast<const ushort4*>((const u16*)x + (size_t)sB * IN_DIM)[l];
                ushort4 vC = reinterpret_cast<const ushort4*>((const u16*)x + (size_t)sC * IN_DIM)[l];
                ushort4 vD = reinterpret_cast<const ushort4*>((const u16*)x + (size_t)sD * IN_DIM)[l];
                a0 += bf2f(vA.x); a1 += bf2f(vA.y); a2 += bf2f(vA.z); a3 += bf2f(vA.w);
                c0 += bf2f(vB.x); c1 += bf2f(vB.y); c2 += bf2f(vB.z); c3 += bf2f(vB.w);
                d0 += bf2f(vC.x); d1 += bf2f(vC.y); d2 += bf2f(vC.z); d3 += bf2f(vC.w);
                e0 += bf2f(vD.x); e1 += bf2f(vD.y); e2 += bf2f(vD.z); e3 += bf2f(vD.w);
            } else {
                float4 vA = reinterpret_cast<const float4*>((const float*)x + (size_t)sA * IN_DIM)[l];
                float4 vB = reinterpret_cast<const float4*>((const float*)x + (size_t)sB * IN_DIM)[l];
                float4 vC = reinterpret_cast<const float4*>((const float*)x + (size_t)sC * IN_DIM)[l];
                float4 vD = reinterpret_cast<const float4*>((const float*)x + (size_t)sD * IN_DIM)[l];
                a0 += vA.x; a1 += vA.y; a2 += vA.z; a3 += vA.w;
                c0 += vB.x; c1 += vB.y; c2 += vB.z; c3 += vB.w;
                d0 += vC.x; d1 += vC.y; d2 += vC.z; d3 += vC.w;
                e0 += vD.x; e1 += vD.y; e2 += vD.z; e3 += vD.w;
            }
        }
        for (; j + 4 < deg; j += 8) {
            int sA = (int)srt[st + j];
            int sB = (int)srt[st + j + 4];
            if (bf) {
                ushort4 vA = reinterpret_cast<const ushort4*>((const u16*)x + (size_t)sA * IN_DIM)[l];
                ushort4 vB = reinterpret_cast<const ushort4*>((const u16*)x + (size_t)sB * IN_DIM)[l];
                a0 += bf2f(vA.x); a1 += bf2f(vA.y); a2 += bf2f(vA.z); a3 += bf2f(vA.w);
                c0 += bf2f(vB.x); c1 += bf2f(vB.y); c2 += bf2f(vB.z); c3 += bf2f(vB.w);
            } else {
                float4 vA = reinterpret_cast<const float4*>((const float*)x + (size_t)sA * IN_DIM)[l];
                float4 vB = reinterpret_cast<const float4*>((const float*)x + (size_t)sB * IN_DIM)[l];
                a0 += vA.x; a1 += vA.y; a2 += vA.z; a3 += vA.w;
                c0 += vB.x; c1 += vB.y; c2 += vB.z; c3 += vB.w;
            }
        }
        if (j < deg) {
            int s = (int)srt[st + j];
            if (bf) {
                ushort4 vv = reinterpret_cast<const ushort4*>((const u16*)x + (size_t)s * IN_DIM)[l];
                a0 += bf2f(vv.x); a1 += bf2f(vv.y); a2 += bf2f(vv.z); a3 += bf2f(vv.w);
            } else {
                float4 vv = reinterpret_cast<const float4*>((const float*)x + (size_t)s * IN_DIM)[l];
                a0 += vv.x; a1 += vv.y; a2 += vv.z; a3 += vv.w;
            }
        }
        a0 += c0 + d0 + e0;
        a1 += c1 + d1 + e1;
        a2 += c2 + d2 + e2;
        a3 += c3 + d3 + e3;
        a0 += __shfl_xor(a0, 8, 64);  a0 += __shfl_xor(a0, 16, 64);
        a1 += __shfl_xor(a1, 8, 64);  a1 += __shfl_xor(a1, 16, 64);
        a2 += __shfl_xor(a2, 8, 64);  a2 += __shfl_xor(a2, 16, 64);
        a3 += __shfl_xor(a3, 8, 64);  a3 += __shfl_xor(a3, 16, 64);
        if (g2 == 0) {
            aggw[wid][half][4 * l + 0] = a0; aggw[wid][half][4 * l + 1] = a1;
            aggw[wid][half][4 * l + 2] = a2; aggw[wid][half][4 * l + 3] = a3;
        }
        float rd0 = 1.0f / fmaxf((float)hist[s0], 1.0f);
        float rd1 = 1.0f / fmaxf((float)hist[s0 + 1], 1.0f);
        float acc0 = bb, acc1 = bb;
        #pragma unroll 8
        for (int k = 0; k < IN_DIM; k++) {
            float wl = tW1l[k * HID_DIM + o];
            float wr = tW1r[k * HID_DIM + o];
            acc0 += (aggw[wid][0][k] * rd0) * wl + xs[s0][k] * wr;
            acc1 += (aggw[wid][1][k] * rd1) * wl + xs[s0 + 1][k] * wr;
        }
        hb[wid * 2][o]     = fmaxf(acc0, 0.0f);
        hb[wid * 2 + 1][o] = fmaxf(acc1, 0.0f);
        int hs = wid * 2 + half;
        float ga = 0.0f, ra = 0.0f;
        #pragma unroll 4
        for (int mm = 0; mm < 16; mm++) {
            int k = g2 * 16 + mm;
            float hv = hb[hs][k];
            ga += hv * tW2l[k * OUT_DIM + l];
            ra += hv * tW2r[k * OUT_DIM + l];
        }
        ga += __shfl_xor(ga, 8, 64);  ga += __shfl_xor(ga, 16, 64);
        ra += __shfl_xor(ra, 8, 64);  ra += __shfl_xor(ra, 16, 64);
        int n = nb + ns;
        if (g2 == 0 && n < N_NODES) {
            __builtin_nontemporal_store(f2bf(ga), &gbuf[(size_t)n * OUT_DIM + l]);
            __builtin_nontemporal_store(ra + tb2[l], &rbuf[(size_t)n * OUT_DIM + l]);
        }
    }
}

__global__ __launch_bounds__(256) void k_l2(
    const u16* __restrict__ gbuf, const float* __restrict__ rbuf,
    const int* __restrict__ qcnt, const u32* __restrict__ qbuf,
    const u32* __restrict__ xw, void* __restrict__ out)
{
    __shared__ int hist[BK], pos[BK], pcur[BK];
    __shared__ int mp[8], mbase[8], mtv;
    __shared__ u32 raw[QC];
    __shared__ u32 srt[QC];
    __shared__ int bfv;
    int t = threadIdx.x;
    if (t < 64) {
        u32 w = xw[t];
        u32 b = (w >> 8) & 0x7fu;
        ull m2 = __ballot(b >= 0x38u && b <= 0x41u);
        if (t == 0) bfv = (__popcll(m2) >= 56) ? 1 : 0;
    }
    if (t < BK) hist[t] = 0;
    int b = blockIdx.x, nb = b * BK;
    if (t < 8) {
        int v = qcnt[t * QSTR + b];
        if (v < 0) v = 0;
        if (v > QCP) v = QCP;
        mp[t] = v;
    }
    __syncthreads();
    if (t == 0) {
        int s = 0;
        for (int p = 0; p < 8; p++) {
            mbase[p] = s;
            int v = mp[p];
            if (s + v > QC) v = QC - s;
            if (v < 0) v = 0;
            mp[p] = v; s += v;
        }
        mtv = s;
    }
    __syncthreads();
    int m = mtv;
    for (int p = 0; p < 8; p++) {
        const u32* qp = qbuf + ((size_t)p * NBKT + b) * QCP;
        int mpp = mp[p], mb = mbase[p];
        for (int i = t; i < mpp; i += 256)
            raw[mb + i] = __builtin_nontemporal_load(&qp[i]);
    }
    __syncthreads();

    for (int i = t; i < m; i += 256)
        atomicAdd(&hist[raw[i] & 63], 1);
    __syncthreads();
    if (t < 64) {
        int v = hist[t];
        int inc = v;
        #pragma unroll
        for (int o = 1; o < 64; o <<= 1) {
            int y = __shfl_up(inc, o, 64);
            if (t >= o) inc += y;
        }
        int ex = inc - v;
        pos[t] = ex; pcur[t] = ex;
    }
    __syncthreads();
    for (int i = t; i < m; i += 256) {
        u32 u = raw[i];
        int p = atomicAdd(&pcur[u & 63], 1);
        srt[p] = u >> 6;
    }
    __syncthreads();

    int grp = t >> 3, l = t & 7;
    for (int r = 0; r < 2; r++) {
        int ns = grp * 2 + r;
        int st = pos[ns], deg = hist[ns];
        float a0 = 0.0f, a1 = 0.0f, a2 = 0.0f, a3 = 0.0f;
        int j = 0;
        for (; j + 3 < deg; j += 4) {
            int v0 = (int)srt[st + j];
            int v1 = (int)srt[st + j + 1];
            int v2 = (int)srt[st + j + 2];
            int v3 = (int)srt[st + j + 3];
            a0 += bf2f(gbuf[(size_t)v0 * OUT_DIM + l]);
            a1 += bf2f(gbuf[(size_t)v1 * OUT_DIM + l]);
            a2 += bf2f(gbuf[(size_t)v2 * OUT_DIM + l]);
            a3 += bf2f(gbuf[(size_t)v3 * OUT_DIM + l]);
        }
        for (; j < deg; j++) a0 += bf2f(gbuf[(size_t)srt[st + j] * OUT_DIM + l]);
        int n = nb + ns;
        if (n < N_NODES) {
            float res = (a0 + a1 + a2 + a3) / fmaxf((float)deg, 1.0f)
                      + rbuf[(size_t)n * OUT_DIM + l];
            size_t oi = (size_t)n * OUT_DIM + l;
            if (bfv) ((u16*)out)[oi] = f2bf(res);
            else     ((float*)out)[oi] = res;
        }
    }
}

extern "C" void kernel_launch(void* const* d_in, const int* in_sizes, int n_in,
                              void* d_out, int out_size, void* d_ws, size_t ws_size,
                              hipStream_t stream) {
    const void* x   = d_in[0];
    const int*  ei  = (const int*)d_in[1];
    const void* W1l = d_in[2];
    const void* b1  = d_in[3];
    const void* W1r = d_in[4];
    const void* W2l = d_in[5];
    const void* b2  = d_in[6];
    const void* W2r = d_in[7];

    // ws layout (4B units); total ~16.1 MB (ws >= 64.4 MB proven earlier)
    int* qcnt    = (int*)d_ws;                       // 8*QSTR
    float* tW1l  = (float*)(qcnt + 8 * QSTR);        // 2048
    float* tW1r  = tW1l + IN_DIM * HID_DIM;          // 2048
    float* tW2l  = tW1r + IN_DIM * HID_DIM;          // 512
    float* tW2r  = tW2l + HID_DIM * OUT_DIM;         // 512
    float* tb1   = tW2r + HID_DIM * OUT_DIM;         // 64
    float* tb2   = tb1 + HID_DIM;                    // 8
    u32* qbuf    = (u32*)(tb2 + OUT_DIM);            // 8*NBKT*QCP (11.2 MB)
    u16* gbuf    = (u16*)(qbuf + (size_t)8 * NBKT * QCP);      // N*8 u16 (1.6 MB)
    float* rbuf  = (float*)(gbuf + (size_t)N_NODES * OUT_DIM); // N*8 f32 (3.2 MB)

    // ---- primary: fused cooperative kernel (qcnt zeroed in-kernel) ----
    const int*  ei_   = ei;
    const u32*  xw_   = (const u32*)x;
    const void* W1l_  = W1l; const void* b1_  = b1;  const void* W1r_ = W1r;
    const void* W2l_  = W2l; const void* b2_  = b2;  const void* W2r_ = W2r;
    int*  qcnt_ = qcnt;  u32* qbuf_ = qbuf;
    float *tW1l_ = tW1l, *tW1r_ = tW1r, *tW2l_ = tW2l, *tW2r_ = tW2r;
    float *tb1_ = tb1, *tb2_ = tb2;
    u16* gbuf_ = gbuf; float* rbuf_ = rbuf; void* out_ = d_out;
    void* kargs[] = {
        (void*)&ei_, (void*)&xw_,
        (void*)&W1l_, (void*)&b1_, (void*)&W1r_,
        (void*)&W2l_, (void*)&b2_, (void*)&W2r_,
        (void*)&qcnt_, (void*)&qbuf_,
        (void*)&tW1l_, (void*)&tW1r_, (void*)&tW2l_, (void*)&tW2r_,
        (void*)&tb1_, (void*)&tb2_,
        (void*)&gbuf_, (void*)&rbuf_, (void*)&out_
    };
    hipError_t err = hipLaunchCooperativeKernel(
        reinterpret_cast<const void*>(&k_fused),
        dim3(NBKT), dim3(256), kargs, 0, stream);

    if (err != hipSuccess) {
        // ---- fallback: R11-proven 3-kernel pipeline ----
        (void)hipGetLastError();   // clear sticky error
        hipMemsetAsync(d_ws, 0, 8 * QSTR * sizeof(int), stream);
        k_part2<<<NCHUNK, 256, 0, stream>>>(ei, (const u32*)x,
                                            W1l, b1, W1r, W2l, b2, W2r,
                                            qcnt, qbuf,
                                            tW1l, tW1r, tW2l, tW2r, tb1, tb2);
        k_l1<<<NBKT, 256, 0, stream>>>(x, qcnt, qbuf,
                                       tW1l, tW1r, tW2l, tW2r, tb1, tb2,
                                       gbuf, rbuf, (const u32*)x);
        k_l2<<<NBKT, 256, 0, stream>>>(gbuf, rbuf, qcnt, qbuf,
                                       (const u32*)x, d_out);
    }
}

// Round 13
// 214.300 us; speedup vs baseline: 3.2728x; 3.2728x over previous
//
#include <hip/hip_runtime.h>

#define N_NODES 100000
#define N_EDGES 1600000
#define IN_DIM 32
#define HID_DIM 64
#define OUT_DIM 8
#define BK 64                         // dst nodes per bucket
#define NBKT ((N_NODES + BK - 1) / BK)    // 1563
#define QC 1280                       // per-bucket total cap (mean 1024, +8 sigma)
#define QCP 224                       // per-(bucket,XCD-partition) cap
#define QSTR 2048                     // qcnt partition stride
#define CHUNK 4096                    // edges per k_part2 block
#define NCHUNK ((N_EDGES + CHUNK - 1) / CHUNK)   // 391

typedef unsigned short u16;
typedef unsigned int u32;
typedef unsigned long long ull;

__device__ __forceinline__ float bf2f(u16 v) {
    return __uint_as_float(((u32)v) << 16);
}

__device__ __forceinline__ u16 f2bf(float f) {
    u32 u = __float_as_uint(f);
    u32 lsb = (u >> 16) & 1u;
    u += 0x7fffu + lsb;
    return (u16)(u >> 16);
}

__device__ __forceinline__ float ldf(const void* p, size_t i, int bf) {
    return bf ? bf2f(((const u16*)p)[i]) : ((const float*)p)[i];
}

// ---- Phase A (R11-proven, verbatim): dtype probe + weight transpose +
//      XCD-partitioned edge partition into 1563 dst-buckets of 64 nodes. ----
__global__ __launch_bounds__(256) void k_part2(
    const int* __restrict__ ei, const u32* __restrict__ xw,
    const void* __restrict__ W1l, const void* __restrict__ b1,
    const void* __restrict__ W1r,
    const void* __restrict__ W2l, const void* __restrict__ b2,
    const void* __restrict__ W2r,
    int* __restrict__ qcnt, u32* __restrict__ qbuf,
    float* __restrict__ tW1l, float* __restrict__ tW1r,
    float* __restrict__ tW2l, float* __restrict__ tW2r,
    float* __restrict__ tb1, float* __restrict__ tb2)
{
    __shared__ int shv, bfv;
    __shared__ int hist[NBKT], gbase[NBKT], lcur[NBKT];   // 18.8 KB
    int t = threadIdx.x;
    int part = blockIdx.x & 7;        // XCD proxy (round-robin dispatch)
    if (t < 64) {   // proven dtype probe, executed per block (same data)
        int v = ei[2 * t + 1];
        ull m1 = __ballot(v == 0);
        u32 wd = xw[t];
        u32 b = (wd >> 8) & 0x7fu;
        ull m2 = __ballot(b >= 0x38u && b <= 0x41u);
        if (t == 0) {
            shv = (m1 == ~0ULL) ? 1 : 0;
            bfv = (__popcll(m2) >= 56) ? 1 : 0;
        }
    }
    for (int i = t; i < NBKT; i += 256) { hist[i] = 0; lcur[i] = 0; }
    __syncthreads();
    int sh = shv, bf = bfv;

    if (blockIdx.x < 16) {        // weight transpose duty (R11-proven indexing)
        for (int i = blockIdx.x * 256 + t; i < HID_DIM * IN_DIM; i += 16 * 256) {
            int o = i / IN_DIM, k = i % IN_DIM;
            tW1l[k * HID_DIM + o] = ldf(W1l, i, bf);
            tW1r[k * HID_DIM + o] = ldf(W1r, i, bf);
        }
        for (int i = blockIdx.x * 256 + t; i < OUT_DIM * HID_DIM; i += 16 * 256) {
            int o = i / HID_DIM, k = i % HID_DIM;
            tW2l[k * OUT_DIM + o] = ldf(W2l, i, bf);
            tW2r[k * OUT_DIM + o] = ldf(W2r, i, bf);
        }
        if (blockIdx.x == 0) {
            if (t < HID_DIM) tb1[t] = ldf(b1, t, bf);
            if (t < OUT_DIM) tb2[t] = ldf(b2, t, bf);
        }
    }

    // edge partition (register-staged, R10-proven shape)
    int e0 = blockIdx.x * CHUNK;
    int myd[16], mys[16];
    #pragma unroll
    for (int i = 0; i < 16; i++) {
        int e = e0 + i * 256 + t;
        if (e < N_EDGES) {
            size_t off = (size_t)e << sh;
            mys[i] = __builtin_nontemporal_load(&ei[off]);
            int d = __builtin_nontemporal_load(&ei[((size_t)N_EDGES << sh) + off]);
            myd[i] = d;
            atomicAdd(&hist[d >> 6], 1);
        } else myd[i] = -1;
    }
    __syncthreads();
    for (int i = t; i < NBKT; i += 256) {
        int h = hist[i];
        gbase[i] = h ? atomicAdd(&qcnt[part * QSTR + i], h) : 0;
    }
    __syncthreads();
    #pragma unroll
    for (int i = 0; i < 16; i++) {
        int d = myd[i];
        if (d >= 0) {
            int bk = d >> 6;
            int p = gbase[bk] + atomicAdd(&lcur[bk], 1);
            if (p < QCP)
                qbuf[((size_t)part * NBKT + bk) * QCP + p] =
                    ((u32)mys[i] << 6) | (u32)(d & 63);
        }
    }
}

// ---- Layer 1 (R11-proven, verbatim) + NEW (R13): persist the sorted
//      lists (srt/pos/hist) to global so k_l2 skips its redundant re-sort
//      (staging 6.4MB + 1.6M LDS atomics + scan + 1.6M scatter). ----
__global__ __launch_bounds__(256, 4) void k_l1(
    const void* __restrict__ x,
    const int* __restrict__ qcnt, const u32* __restrict__ qbuf,
    const float* __restrict__ tW1l, const float* __restrict__ tW1r,
    const float* __restrict__ tW2l, const float* __restrict__ tW2r,
    const float* __restrict__ tb1, const float* __restrict__ tb2,
    u16* __restrict__ gbuf, float* __restrict__ rbuf,
    int* __restrict__ g_hist, int* __restrict__ g_pos,
    u32* __restrict__ g_srt,
    const u32* __restrict__ xw)
{
    __shared__ int hist[BK], pos[BK], pcur[BK];
    __shared__ int mp[8], mbase[8], mtv;
    __shared__ u32 raw[QC];
    __shared__ u32 srt[QC];
    __shared__ float xs[BK][IN_DIM];
    __shared__ float aggw[4][2][IN_DIM];
    __shared__ float hb[8][HID_DIM + 1];
    __shared__ int bfv;

    int t = threadIdx.x;
    if (t < 64) {   // dtype probe (proven)
        u32 wd = xw[t];
        u32 b = (wd >> 8) & 0x7fu;
        ull m2 = __ballot(b >= 0x38u && b <= 0x41u);
        if (t == 0) bfv = (__popcll(m2) >= 56) ? 1 : 0;
    }
    if (t < BK) hist[t] = 0;
    int b = blockIdx.x, nb = b * BK;
    if (t < 8) {
        int v = qcnt[t * QSTR + b];
        if (v < 0) v = 0;
        if (v > QCP) v = QCP;
        mp[t] = v;
    }
    __syncthreads();
    int bf = bfv;
    if (t == 0) {       // sequential clamp so total fits raw/srt (QC)
        int s = 0;
        for (int p = 0; p < 8; p++) {
            mbase[p] = s;
            int v = mp[p];
            if (s + v > QC) v = QC - s;
            if (v < 0) v = 0;
            mp[p] = v; s += v;
        }
        mtv = s;
    }
    __syncthreads();
    int m = mtv;

    // stage the 8 partition segments into raw[] (coalesced reads)
    for (int p = 0; p < 8; p++) {
        const u32* qp = qbuf + ((size_t)p * NBKT + b) * QCP;
        int mpp = mp[p], mb = mbase[p];
        for (int i = t; i < mpp; i += 256)
            raw[mb + i] = __builtin_nontemporal_load(&qp[i]);
    }

    // stage self rows -> xs (f32), guarded for the partial last bucket
    if (bf) {
        const u32* xr = (const u32*)x + (size_t)nb * (IN_DIM / 2);
        int lim = ((N_NODES - nb < BK) ? (N_NODES - nb) : BK) * (IN_DIM / 2);
        for (int i = t; i < BK * (IN_DIM / 2); i += 256) {
            u32 w = (i < lim) ? xr[i] : 0u;
            int r = i >> 4, c = i & 15;
            xs[r][2 * c]     = bf2f((u16)w);
            xs[r][2 * c + 1] = bf2f((u16)(w >> 16));
        }
    } else {
        const float* xr = (const float*)x + (size_t)nb * IN_DIM;
        int lim = ((N_NODES - nb < BK) ? (N_NODES - nb) : BK) * IN_DIM;
        for (int i = t; i < BK * IN_DIM; i += 256)
            xs[i >> 5][i & 31] = (i < lim) ? xr[i] : 0.0f;
    }
    __syncthreads();

    // ---- counting sort (R8-proven): histogram -> 1-wave scan -> scatter ----
    for (int i = t; i < m; i += 256)
        atomicAdd(&hist[raw[i] & 63], 1);
    __syncthreads();
    if (t < 64) {
        int v = hist[t];
        int inc = v;
        #pragma unroll
        for (int o = 1; o < 64; o <<= 1) {
            int y = __shfl_up(inc, o, 64);
            if (t >= o) inc += y;
        }
        int ex = inc - v;
        pos[t] = ex; pcur[t] = ex;
    }
    __syncthreads();
    for (int i = t; i < m; i += 256) {
        u32 u = raw[i];
        int p = atomicAdd(&pcur[u & 63], 1);
        srt[p] = u >> 6;
    }
    __syncthreads();

    // ---- NEW: persist sorted lists for k_l2 (coalesced nt streaming) ----
    if (t < 64) {
        __builtin_nontemporal_store(hist[t], &g_hist[(size_t)b * 64 + t]);
        __builtin_nontemporal_store(pos[t], &g_pos[(size_t)b * 64 + t]);
    }
    for (int i = t; i < m; i += 256)
        __builtin_nontemporal_store(srt[i], &g_srt[(size_t)b * QC + i]);

    // ---- per-pair gather (R8-proven ILP-4 loop) + dense + proj ----
    int wid = t >> 6, lane = t & 63;
    int half = lane >> 5, g2 = (lane >> 3) & 3, l = lane & 7;
    int o = lane;
    float bb = tb1[o];
    for (int pr = 0; pr < 8; pr++) {
        int s0 = pr * 8 + wid * 2;
        int ns = s0 + half;
        int st = pos[ns], deg = hist[ns];
        float a0 = 0, a1 = 0, a2 = 0, a3 = 0;
        float c0 = 0, c1 = 0, c2 = 0, c3 = 0;
        float d0 = 0, d1 = 0, d2 = 0, d3 = 0;
        float e0 = 0, e1 = 0, e2 = 0, e3 = 0;
        int j = g2;
        for (; j + 12 < deg; j += 16) {   // 4 independent neighbor loads in flight
            int sA = (int)srt[st + j];
            int sB = (int)srt[st + j + 4];
            int sC = (int)srt[st + j + 8];
            int sD = (int)srt[st + j + 12];
            if (bf) {
                ushort4 vA = reinterpret_cast<const ushort4*>((const u16*)x + (size_t)sA * IN_DIM)[l];
                ushort4 vB = reinterpret_cast<const ushort4*>((const u16*)x + (size_t)sB * IN_DIM)[l];
                ushort4 vC = reinterpret_cast<const ushort4*>((const u16*)x + (size_t)sC * IN_DIM)[l];
                ushort4 vD = reinterpret_cast<const ushort4*>((const u16*)x + (size_t)sD * IN_DIM)[l];
                a0 += bf2f(vA.x); a1 += bf2f(vA.y); a2 += bf2f(vA.z); a3 += bf2f(vA.w);
                c0 += bf2f(vB.x); c1 += bf2f(vB.y); c2 += bf2f(vB.z); c3 += bf2f(vB.w);
                d0 += bf2f(vC.x); d1 += bf2f(vC.y); d2 += bf2f(vC.z); d3 += bf2f(vC.w);
                e0 += bf2f(vD.x); e1 += bf2f(vD.y); e2 += bf2f(vD.z); e3 += bf2f(vD.w);
            } else {
                float4 vA = reinterpret_cast<const float4*>((const float*)x + (size_t)sA * IN_DIM)[l];
                float4 vB = reinterpret_cast<const float4*>((const float*)x + (size_t)sB * IN_DIM)[l];
                float4 vC = reinterpret_cast<const float4*>((const float*)x + (size_t)sC * IN_DIM)[l];
                float4 vD = reinterpret_cast<const float4*>((const float*)x + (size_t)sD * IN_DIM)[l];
                a0 += vA.x; a1 += vA.y; a2 += vA.z; a3 += vA.w;
                c0 += vB.x; c1 += vB.y; c2 += vB.z; c3 += vB.w;
                d0 += vC.x; d1 += vC.y; d2 += vC.z; d3 += vC.w;
                e0 += vD.x; e1 += vD.y; e2 += vD.z; e3 += vD.w;
            }
        }
        for (; j + 4 < deg; j += 8) {     // 2-way remainder
            int sA = (int)srt[st + j];
            int sB = (int)srt[st + j + 4];
            if (bf) {
                ushort4 vA = reinterpret_cast<const ushort4*>((const u16*)x + (size_t)sA * IN_DIM)[l];
                ushort4 vB = reinterpret_cast<const ushort4*>((const u16*)x + (size_t)sB * IN_DIM)[l];
                a0 += bf2f(vA.x); a1 += bf2f(vA.y); a2 += bf2f(vA.z); a3 += bf2f(vA.w);
                c0 += bf2f(vB.x); c1 += bf2f(vB.y); c2 += bf2f(vB.z); c3 += bf2f(vB.w);
            } else {
                float4 vA = reinterpret_cast<const float4*>((const float*)x + (size_t)sA * IN_DIM)[l];
                float4 vB = reinterpret_cast<const float4*>((const float*)x + (size_t)sB * IN_DIM)[l];
                a0 += vA.x; a1 += vA.y; a2 += vA.z; a3 += vA.w;
                c0 += vB.x; c1 += vB.y; c2 += vB.z; c3 += vB.w;
            }
        }
        if (j < deg) {                    // tail (at most one per group)
            int s = (int)srt[st + j];
            if (bf) {
                ushort4 vv = reinterpret_cast<const ushort4*>((const u16*)x + (size_t)s * IN_DIM)[l];
                a0 += bf2f(vv.x); a1 += bf2f(vv.y); a2 += bf2f(vv.z); a3 += bf2f(vv.w);
            } else {
                float4 vv = reinterpret_cast<const float4*>((const float*)x + (size_t)s * IN_DIM)[l];
                a0 += vv.x; a1 += vv.y; a2 += vv.z; a3 += vv.w;
            }
        }
        a0 += c0 + d0 + e0;
        a1 += c1 + d1 + e1;
        a2 += c2 + d2 + e2;
        a3 += c3 + d3 + e3;
        a0 += __shfl_xor(a0, 8, 64);  a0 += __shfl_xor(a0, 16, 64);
        a1 += __shfl_xor(a1, 8, 64);  a1 += __shfl_xor(a1, 16, 64);
        a2 += __shfl_xor(a2, 8, 64);  a2 += __shfl_xor(a2, 16, 64);
        a3 += __shfl_xor(a3, 8, 64);  a3 += __shfl_xor(a3, 16, 64);
        if (g2 == 0) {                    // wave-private: no barrier needed
            aggw[wid][half][4 * l + 0] = a0; aggw[wid][half][4 * l + 1] = a1;
            aggw[wid][half][4 * l + 2] = a2; aggw[wid][half][4 * l + 3] = a3;
        }
        // dense layer 1 (each lane = output o, both nodes of the pair)
        float rd0 = 1.0f / fmaxf((float)hist[s0], 1.0f);
        float rd1 = 1.0f / fmaxf((float)hist[s0 + 1], 1.0f);
        float acc0 = bb, acc1 = bb;
        #pragma unroll 8
        for (int k = 0; k < IN_DIM; k++) {
            float wl = tW1l[k * HID_DIM + o];
            float wr = tW1r[k * HID_DIM + o];
            acc0 += (aggw[wid][0][k] * rd0) * wl + xs[s0][k] * wr;
            acc1 += (aggw[wid][1][k] * rd1) * wl + xs[s0 + 1][k] * wr;
        }
        hb[wid * 2][o]     = fmaxf(acc0, 0.0f);   // wave-private rows
        hb[wid * 2 + 1][o] = fmaxf(acc1, 0.0f);
        // layer-2 projections: g = h@W2l^T (bf16-packed), r = h@W2r^T + b2
        int hs = wid * 2 + half;
        float ga = 0.0f, ra = 0.0f;
        #pragma unroll 4
        for (int mm = 0; mm < 16; mm++) {
            int k = g2 * 16 + mm;
            float hv = hb[hs][k];
            ga += hv * tW2l[k * OUT_DIM + l];
            ra += hv * tW2r[k * OUT_DIM + l];
        }
        ga += __shfl_xor(ga, 8, 64);  ga += __shfl_xor(ga, 16, 64);
        ra += __shfl_xor(ra, 8, 64);  ra += __shfl_xor(ra, 16, 64);
        int n = nb + ns;
        if (g2 == 0 && n < N_NODES) {
            __builtin_nontemporal_store(f2bf(ga), &gbuf[(size_t)n * OUT_DIM + l]);
            __builtin_nontemporal_store(ra + tb2[l], &rbuf[(size_t)n * OUT_DIM + l]);
        }
    }
}

// ---- Layer 2 (R13): load persisted sorted lists (coalesced), go straight
//      to the R8-proven 8-lane/node 4-way-ILP gather. Sort work deleted. ----
__global__ __launch_bounds__(256) void k_l2(
    const u16* __restrict__ gbuf, const float* __restrict__ rbuf,
    const int* __restrict__ g_hist, const int* __restrict__ g_pos,
    const u32* __restrict__ g_srt,
    const u32* __restrict__ xw, void* __restrict__ out)
{
    __shared__ int hist[BK], pos[BK];
    __shared__ u32 srt[QC];
    __shared__ int mtv, bfv;
    int t = threadIdx.x;
    if (t < 64) {   // output-dtype probe (proven)
        u32 w = xw[t];
        u32 b = (w >> 8) & 0x7fu;
        ull m2 = __ballot(b >= 0x38u && b <= 0x41u);
        if (t == 0) bfv = (__popcll(m2) >= 56) ? 1 : 0;
    }
    int b = blockIdx.x, nb = b * BK;
    if (t < 64) {
        int h = g_hist[(size_t)b * 64 + t];
        int p = g_pos[(size_t)b * 64 + t];
        hist[t] = h; pos[t] = p;
        if (t == 63) mtv = p + h;      // total entries for this bucket
    }
    __syncthreads();
    int m = mtv;
    const u32* gs = g_srt + (size_t)b * QC;
    for (int i = t; i < m; i += 256)
        srt[i] = __builtin_nontemporal_load(&gs[i]);
    __syncthreads();

    int grp = t >> 3, l = t & 7;          // 32 groups x 8 lanes
    for (int r = 0; r < 2; r++) {
        int ns = grp * 2 + r;             // node slot 0..63
        int st = pos[ns], deg = hist[ns];
        float a0 = 0.0f, a1 = 0.0f, a2 = 0.0f, a3 = 0.0f;
        int j = 0;
        for (; j + 3 < deg; j += 4) {
            int v0 = (int)srt[st + j];
            int v1 = (int)srt[st + j + 1];
            int v2 = (int)srt[st + j + 2];
            int v3 = (int)srt[st + j + 3];
            a0 += bf2f(gbuf[(size_t)v0 * OUT_DIM + l]);
            a1 += bf2f(gbuf[(size_t)v1 * OUT_DIM + l]);
            a2 += bf2f(gbuf[(size_t)v2 * OUT_DIM + l]);
            a3 += bf2f(gbuf[(size_t)v3 * OUT_DIM + l]);
        }
        for (; j < deg; j++) a0 += bf2f(gbuf[(size_t)srt[st + j] * OUT_DIM + l]);
        int n = nb + ns;
        if (n < N_NODES) {
            float res = (a0 + a1 + a2 + a3) / fmaxf((float)deg, 1.0f)
                      + rbuf[(size_t)n * OUT_DIM + l];
            size_t oi = (size_t)n * OUT_DIM + l;
            if (bfv) ((u16*)out)[oi] = f2bf(res);
            else     ((float*)out)[oi] = res;
        }
    }
}

extern "C" void kernel_launch(void* const* d_in, const int* in_sizes, int n_in,
                              void* d_out, int out_size, void* d_ws, size_t ws_size,
                              hipStream_t stream) {
    const void* x   = d_in[0];
    const int*  ei  = (const int*)d_in[1];
    const void* W1l = d_in[2];
    const void* b1  = d_in[3];
    const void* W1r = d_in[4];
    const void* W2l = d_in[5];
    const void* b2  = d_in[6];
    const void* W2r = d_in[7];

    // ws layout (4B units); total ~25 MB (ws >= 64.4 MB proven earlier)
    int* qcnt    = (int*)d_ws;                       // 8*QSTR (memset)
    float* tW1l  = (float*)(qcnt + 8 * QSTR);        // 2048
    float* tW1r  = tW1l + IN_DIM * HID_DIM;          // 2048
    float* tW2l  = tW1r + IN_DIM * HID_DIM;          // 512
    float* tW2r  = tW2l + HID_DIM * OUT_DIM;         // 512
    float* tb1   = tW2r + HID_DIM * OUT_DIM;         // 64
    float* tb2   = tb1 + HID_DIM;                    // 8
    u32* qbuf    = (u32*)(tb2 + OUT_DIM);            // 8*NBKT*QCP (11.2 MB)
    u16* gbuf    = (u16*)(qbuf + (size_t)8 * NBKT * QCP);      // N*8 u16 (1.6 MB)
    float* rbuf  = (float*)(gbuf + (size_t)N_NODES * OUT_DIM); // N*8 f32 (3.2 MB)
    int* g_hist  = (int*)(rbuf + (size_t)N_NODES * OUT_DIM);   // NBKT*64 (0.4 MB)
    int* g_pos   = g_hist + (size_t)NBKT * 64;                 // NBKT*64 (0.4 MB)
    u32* g_srt   = (u32*)(g_pos + (size_t)NBKT * 64);          // NBKT*QC (8.0 MB)

    // zero qcnt only (64 KB)
    hipMemsetAsync(d_ws, 0, 8 * QSTR * sizeof(int), stream);

    k_part2<<<NCHUNK, 256, 0, stream>>>(ei, (const u32*)x,
                                        W1l, b1, W1r, W2l, b2, W2r,
                                        qcnt, qbuf,
                                        tW1l, tW1r, tW2l, tW2r, tb1, tb2);
    k_l1<<<NBKT, 256, 0, stream>>>(x, qcnt, qbuf,
                                   tW1l, tW1r, tW2l, tW2r, tb1, tb2,
                                   gbuf, rbuf, g_hist, g_pos, g_srt,
                                   (const u32*)x);
    k_l2<<<NBKT, 256, 0, stream>>>(gbuf, rbuf, g_hist, g_pos, g_srt,
                                   (const u32*)x, d_out);
}